// Round 10
// baseline (262.230 us; speedup 1.0000x reference)
//
#include <hip/hip_runtime.h>
#include <hip/hip_bf16.h>

// B=2, L=4096, D=768, H=12, HS=64, SCALE=0.125. Inputs/outputs fp32; bf16 MFMA inside.
#define LQ 4096
#define DQ 768
#define NH 12
#define NB 2

typedef __attribute__((ext_vector_type(8))) short short8;
typedef __attribute__((ext_vector_type(2))) unsigned uint2v;
typedef __attribute__((ext_vector_type(4))) float f32x4;

__device__ __forceinline__ short f2bf(float f) {
    union { float f; unsigned u; } v; v.f = f;
    unsigned r = v.u + 0x7FFFu + ((v.u >> 16) & 1u);   // RNE
    return (short)(r >> 16);
}

__device__ __forceinline__ unsigned pk2(float a, float b) {
    float2 t; t.x = a; t.y = b;
    __hip_bfloat162 h = __float22bfloat162_rn(t);
    unsigned u; __builtin_memcpy(&u, &h, 4);
    return u;
}

__device__ __forceinline__ f32x4 mfma16(short8 a, short8 b, f32x4 c) {
    return __builtin_amdgcn_mfma_f32_16x16x32_bf16(a, b, c, 0, 0, 0);
}

// sqrt(0.125 * log2(e)): Qf pre-scaled so S^T = (Q')(Q')^T is directly in exp2 domain
#define SQRT_C 0.424660891f

// fp32 -> bf16 bulk convert, n multiple of 1024
__global__ __launch_bounds__(256) void cvtw(const float* __restrict__ a,
                                            short* __restrict__ o) {
    int i = blockIdx.x * 256 + threadIdx.x;
    float4 v = ((const float4*)a)[i];
    *(uint2v*)&o[i * 4] = (uint2v){pk2(v.x, v.y), pk2(v.z, v.w)};
}

// Fragment-major layouts (per bh, per 64-key tile = 4096 shorts, 8 chunks of 512):
//  Qf chunk(t4,s): lane L holds Q[key=16*t4+(L&15)][d=32*s+8*(L>>4)+j]  (SCALED by SQRT_C)
//  Vf chunk(t2,ks): lane L holds Q[key=32*ks+8*(L>>4)+j][d=16*t2+(L&15)] (unscaled)

// C[M,N] = A[M,K] @ W[N,K]^T, M=8192, N=768, K=768. A bf16; W bf16 (WB) or fp32.
// Tile 128m x 64n, BK=64, 768 blocks, XCD-affine m. MODE 0: C fp32 row-major.
// MODE 1: emit Qf (scaled) + Vf fragment-major bf16 via LDS scatter->coalesced flush.
template <bool WB, int MODE>
__global__ __launch_bounds__(256, 3) void gemm_nt(const short* __restrict__ A,
                                                  const void* __restrict__ Wp,
                                                  void* __restrict__ Cp,
                                                  short* __restrict__ Vf) {
    __shared__ short As[128 * 72];   // 64 K-elems + 8 pad; reused as F scratch in epilogue
    __shared__ short Bs[64 * 72];
    const int t = threadIdx.x;
    const int lane = t & 63, w = t >> 6;
    const int lr = lane & 15, qd = lane >> 4;
    const int wm = (w & 1) * 64, wn = (w >> 1) * 32;
    const int lin = blockIdx.x;
    const int xcd = lin & 7, jj = lin >> 3;
    const int nt = jj % 12, mt = (jj / 12) * 8 + xcd;
    const int m0 = mt * 128, n0 = nt * 64;

    f32x4 acc[4][2];
#pragma unroll
    for (int i = 0; i < 4; ++i)
#pragma unroll
        for (int j = 0; j < 2; ++j) acc[i][j] = (f32x4){0.f, 0.f, 0.f, 0.f};

#pragma unroll
    for (int u = 0; u < 4; ++u) {
        int c = t + 256 * u, row = c >> 3, col = (c & 7) << 3;
        *(short8*)&As[row * 72 + col] = *(const short8*)&A[(size_t)(m0 + row) * DQ + col];
    }
    if (WB) {
        const short* W = (const short*)Wp;
#pragma unroll
        for (int u = 0; u < 2; ++u) {
            int c = t + 256 * u, row = c >> 3, col = (c & 7) << 3;
            *(short8*)&Bs[row * 72 + col] = *(const short8*)&W[(size_t)(n0 + row) * DQ + col];
        }
    } else {
        const float* W = (const float*)Wp;
#pragma unroll
        for (int u = 0; u < 4; ++u) {
            int c = t + 256 * u, row = c >> 4, col = (c & 15) << 2;
            float4 v = *(const float4*)&W[(size_t)(n0 + row) * DQ + col];
            *(uint2v*)&Bs[row * 72 + col] = (uint2v){pk2(v.x, v.y), pk2(v.z, v.w)};
        }
    }
    __syncthreads();

    for (int kt = 0; kt < 12; ++kt) {
        short8 ra[4], rbw[2]; float4 rb[4];
        if (kt < 11) {
            const int k0 = (kt + 1) * 64;
#pragma unroll
            for (int u = 0; u < 4; ++u) {
                int c = t + 256 * u, row = c >> 3, col = (c & 7) << 3;
                ra[u] = *(const short8*)&A[(size_t)(m0 + row) * DQ + k0 + col];
            }
            if (WB) {
                const short* W = (const short*)Wp;
#pragma unroll
                for (int u = 0; u < 2; ++u) {
                    int c = t + 256 * u, row = c >> 3, col = (c & 7) << 3;
                    rbw[u] = *(const short8*)&W[(size_t)(n0 + row) * DQ + k0 + col];
                }
            } else {
                const float* W = (const float*)Wp;
#pragma unroll
                for (int u = 0; u < 4; ++u) {
                    int c = t + 256 * u, row = c >> 4, col = (c & 15) << 2;
                    rb[u] = *(const float4*)&W[(size_t)(n0 + row) * DQ + k0 + col];
                }
            }
        }
#pragma unroll
        for (int s = 0; s < 2; ++s) {
            short8 af[4], bf[2];
#pragma unroll
            for (int i = 0; i < 4; ++i)
                af[i] = *(short8*)&As[(wm + 16 * i + lr) * 72 + 32 * s + qd * 8];
#pragma unroll
            for (int j = 0; j < 2; ++j)
                bf[j] = *(short8*)&Bs[(wn + 16 * j + lr) * 72 + 32 * s + qd * 8];
#pragma unroll
            for (int i = 0; i < 4; ++i)
#pragma unroll
                for (int j = 0; j < 2; ++j)
                    acc[i][j] = mfma16(af[i], bf[j], acc[i][j]);
        }
        if (kt < 11) {
            __syncthreads();
#pragma unroll
            for (int u = 0; u < 4; ++u) {
                int c = t + 256 * u, row = c >> 3, col = (c & 7) << 3;
                *(short8*)&As[row * 72 + col] = ra[u];
            }
            if (WB) {
#pragma unroll
                for (int u = 0; u < 2; ++u) {
                    int c = t + 256 * u, row = c >> 3, col = (c & 7) << 3;
                    *(short8*)&Bs[row * 72 + col] = rbw[u];
                }
            } else {
#pragma unroll
                for (int u = 0; u < 4; ++u) {
                    int c = t + 256 * u, row = c >> 4, col = (c & 15) << 2;
                    *(uint2v*)&Bs[row * 72 + col] = (uint2v){pk2(rb[u].x, rb[u].y), pk2(rb[u].z, rb[u].w)};
                }
            }
            __syncthreads();
        }
    }

    if (MODE == 0) {
#pragma unroll
        for (int i = 0; i < 4; ++i)
#pragma unroll
            for (int j = 0; j < 2; ++j) {
                const int row0 = m0 + wm + 16 * i + qd * 4;
                const int col = n0 + wn + 16 * j + lr;
#pragma unroll
                for (int r = 0; r < 4; ++r)
                    ((float*)Cp)[(size_t)(row0 + r) * DQ + col] = acc[i][j][r];
            }
    } else {
        // tile = keys (m0&4095)..+127 of bh = (m0>>12)*12 + nt, dims 0..63 (hs)
        short* Qf = (short*)Cp;
        short* F = As;                                   // 8192-short scratch
        const int bh = (m0 >> 12) * NH + nt;
        const size_t gbase = (size_t)bh * (LQ * 64) + (size_t)(((m0 & 4095) >> 6) << 12);
        __syncthreads();
        // ---- Vf staging (unscaled): packed b64 scatter ----
#pragma unroll
        for (int i = 0; i < 4; ++i)
#pragma unroll
            for (int j = 0; j < 2; ++j) {
                const int kl = wm + 16 * i + qd * 4;     // key base (4 consecutive)
                const int hs = wn + 16 * j + lr;         // d
                const int fi = ((kl >> 6) << 12) + ((((hs >> 4) << 1) + ((kl >> 5) & 1)) << 9)
                             + (((hs & 15) + (((kl >> 3) & 3) << 4)) << 3) + (kl & 7);
                *(uint2v*)&F[fi] = (uint2v){pk2(acc[i][j][0], acc[i][j][1]),
                                            pk2(acc[i][j][2], acc[i][j][3])};
            }
        __syncthreads();
#pragma unroll
        for (int p = 0; p < 4; ++p) {
            int u = t + 256 * p;
            *(short8*)&Vf[gbase + (size_t)u * 8] = *(short8*)&F[u * 8];
        }
        __syncthreads();
        // ---- Qf staging (scaled by SQRT_C): b16 scatter ----
#pragma unroll
        for (int i = 0; i < 4; ++i)
#pragma unroll
            for (int j = 0; j < 2; ++j) {
                const int hs = wn + 16 * j + lr;
#pragma unroll
                for (int r = 0; r < 4; ++r) {
                    const int key = wm + 16 * i + qd * 4 + r;
                    const int fi = ((key >> 6) << 12) + (((((key >> 4) & 3) << 1) + (hs >> 5)) << 9)
                                 + (((qd * 4 + r) + (((hs >> 3) & 3) << 4)) << 3) + (hs & 7);
                    F[fi] = f2bf(acc[i][j][r] * SQRT_C);
                }
            }
        __syncthreads();
#pragma unroll
        for (int p = 0; p < 4; ++p) {
            int u = t + 256 * p;
            *(short8*)&Qf[gbase + (size_t)u * 8] = *(short8*)&F[u * 8];
        }
    }
}

// Barrier-free flash attention, K=V=Q, shift-0 softmax. Fragments load coalesced
// from fragment-major global layouts (L2-resident). Qf pre-scaled -> S^T already in
// exp2 domain (no mul). Row-sum l via MFMA with an all-ones B operand (idle MFMA
// pipe instead of VALU adds); C-layout puts l[query qd*4+r] in lacc[i][r] directly.
__global__ __launch_bounds__(256, 3) void attn(const short* __restrict__ Qf,
                                               const short* __restrict__ Vf,
                                               short* __restrict__ O) {
    const int linear = blockIdx.x;
    const int xcd = linear & 7, slot = linear >> 3;        // 768 blocks, 8 XCDs
    const int bh = 3 * xcd + (slot >> 5);                  // 3 bh per XCD (L2-resident)
    const int qtile = slot & 31;                           // 32 q-tiles of 128
    const int t = threadIdx.x;
    const int lane = t & 63, w = t >> 6;
    const int lr = lane & 15, qd = lane >> 4;

    __shared__ short Ps[4][2][16 * 72];                    // [wave][m-tile][q][key]

    const short* Qbh = Qf + (size_t)bh * (LQ * 64);
    const short* Vbh = Vf + (size_t)bh * (LQ * 64);
    const int q0 = qtile * 128 + w * 32;

    const short one_bf = (short)0x3F80;                    // bf16 1.0
    short8 ones;
#pragma unroll
    for (int j = 0; j < 8; ++j) ones[j] = one_bf;

    // Q B-frags: chunk-linear addr = g*1024 + s*512 + lane*8
    short8 aq[2][2];
#pragma unroll
    for (int i = 0; i < 2; ++i) {
        const int g = (q0 >> 4) + i;
#pragma unroll
        for (int s = 0; s < 2; ++s)
            aq[i][s] = *(const short8*)&Qbh[g * 1024 + s * 512 + lane * 8];
    }

    f32x4 oacc[2][4], lacc[2];
#pragma unroll
    for (int i = 0; i < 2; ++i) {
        lacc[i] = (f32x4){0.f, 0.f, 0.f, 0.f};
#pragma unroll
        for (int t2 = 0; t2 < 4; ++t2) oacc[i][t2] = (f32x4){0.f, 0.f, 0.f, 0.f};
    }

    // prologue: kf for kb=0
    short8 kf[4][2];
#pragma unroll
    for (int t4 = 0; t4 < 4; ++t4)
#pragma unroll
        for (int s = 0; s < 2; ++s)
            kf[t4][s] = *(const short8*)&Qbh[(t4 * 2 + s) * 512 + lane * 8];

    for (int kb = 0; kb < LQ / 64; ++kb) {
        // current V^T frags + next-iter K frags: coalesced b128, issued up front
        short8 vb[4][2];
#pragma unroll
        for (int t2 = 0; t2 < 4; ++t2)
#pragma unroll
            for (int ks = 0; ks < 2; ++ks)
                vb[t2][ks] = *(const short8*)&Vbh[kb * 4096 + (t2 * 2 + ks) * 512 + lane * 8];
        short8 kfn[4][2];
        if (kb < LQ / 64 - 1) {
#pragma unroll
            for (int t4 = 0; t4 < 4; ++t4)
#pragma unroll
                for (int s = 0; s < 2; ++s)
                    kfn[t4][s] = *(const short8*)&Qbh[(kb + 1) * 4096 + (t4 * 2 + s) * 512 + lane * 8];
        }

        // S^T already in exp2 domain; p = exp2(s); packed b64 Ps writes; PV + l-MFMA
#pragma unroll
        for (int i = 0; i < 2; ++i) {
            f32x4 sacc[4];
#pragma unroll
            for (int t4 = 0; t4 < 4; ++t4) {
                sacc[t4] = (f32x4){0.f, 0.f, 0.f, 0.f};
#pragma unroll
                for (int s = 0; s < 2; ++s)
                    sacc[t4] = mfma16(kf[t4][s], aq[i][s], sacc[t4]);
            }
#pragma unroll
            for (int t4 = 0; t4 < 4; ++t4) {
                float p0 = __builtin_amdgcn_exp2f(sacc[t4][0]);
                float p1 = __builtin_amdgcn_exp2f(sacc[t4][1]);
                float p2 = __builtin_amdgcn_exp2f(sacc[t4][2]);
                float p3 = __builtin_amdgcn_exp2f(sacc[t4][3]);
                *(uint2v*)&Ps[w][i][lr * 72 + 16 * t4 + 4 * qd] =
                    (uint2v){pk2(p0, p1), pk2(p2, p3)};
            }
#pragma unroll
            for (int ks = 0; ks < 2; ++ks) {
                short8 pa = *(short8*)&Ps[w][i][lr * 72 + 32 * ks + qd * 8];
#pragma unroll
                for (int t2 = 0; t2 < 4; ++t2)
                    oacc[i][t2] = mfma16(pa, vb[t2][ks], oacc[i][t2]);
                lacc[i] = mfma16(pa, ones, lacc[i]);   // row-sum on the MFMA pipe
            }
        }
#pragma unroll
        for (int t4 = 0; t4 < 4; ++t4)
#pragma unroll
            for (int s = 0; s < 2; ++s) kf[t4][s] = kfn[t4][s];
    }

    // l for query qd*4+r is lacc[i][r] in every lane (all ones-columns identical)
    const int b = bh / NH, h = bh % NH;
#pragma unroll
    for (int i = 0; i < 2; ++i) {
        float inv[4];
#pragma unroll
        for (int r = 0; r < 4; ++r) inv[r] = 1.0f / lacc[i][r];
#pragma unroll
        for (int t2 = 0; t2 < 4; ++t2)
#pragma unroll
            for (int r = 0; r < 4; ++r) {
                int lq = q0 + 16 * i + qd * 4 + r;
                int e = h * 64 + 16 * t2 + lr;
                O[((size_t)(b * LQ + lq)) * DQ + e] = f2bf(oacc[i][t2][r] * inv[r]);
            }
    }
}

extern "C" void kernel_launch(void* const* d_in, const int* in_sizes, int n_in,
                              void* d_out, int out_size, void* d_ws, size_t ws_size,
                              hipStream_t stream) {
    (void)in_sizes; (void)n_in; (void)out_size;
    const float* x  = (const float*)d_in[0];   // fp32 [2,4096,768]
    const float* Wq = (const float*)d_in[1];   // fp32 [768,768]
    const float* Wo = (const float*)d_in[2];   // fp32 [768,768]
    float* out = (float*)d_out;                // fp32 [2,4096,768]

    const size_t NQ = (size_t)NB * NH * LQ * 64;         // 6,291,456 elements
    short* Qf  = (short*)d_ws;                           // fragment-major scaled Q
    short* Vfb = Qf + NQ;                                // fragment-major unscaled Q (V)
    short* Ows = Vfb + NQ;                               // xb, then attention out
    short* Wqb = Ows + NQ;                               // bf16 Wq (optional)
    short* Wob = Wqb + (size_t)DQ * DQ;                  // bf16 Wo (optional)
    const size_t need = (3 * NQ + 2 * (size_t)DQ * DQ) * sizeof(short);

    cvtw<<<(NB * LQ * DQ) / 1024, 256, 0, stream>>>(x, Ows);
    if (ws_size >= need) {
        cvtw<<<(DQ * DQ) / 1024, 256, 0, stream>>>(Wq, Wqb);
        cvtw<<<(DQ * DQ) / 1024, 256, 0, stream>>>(Wo, Wob);
        gemm_nt<true, 1><<<768, 256, 0, stream>>>(Ows, Wqb, Qf, Vfb);
        attn<<<768, 256, 0, stream>>>(Qf, Vfb, Ows);
        gemm_nt<true, 0><<<768, 256, 0, stream>>>(Ows, Wob, out, nullptr);
    } else {
        gemm_nt<false, 1><<<768, 256, 0, stream>>>(Ows, Wq, Qf, Vfb);
        attn<<<768, 256, 0, stream>>>(Qf, Vfb, Ows);
        gemm_nt<false, 0><<<768, 256, 0, stream>>>(Ows, Wo, out, nullptr);
    }
}

// Round 11
// 253.714 us; speedup vs baseline: 1.0336x; 1.0336x over previous
//
#include <hip/hip_runtime.h>
#include <hip/hip_bf16.h>

// B=2, L=4096, D=768, H=12, HS=64, SCALE=0.125. Inputs/outputs fp32; bf16 MFMA inside.
#define LQ 4096
#define DQ 768
#define NH 12
#define NB 2

typedef __attribute__((ext_vector_type(8))) short short8;
typedef __attribute__((ext_vector_type(2))) unsigned uint2v;
typedef __attribute__((ext_vector_type(4))) float f32x4;

__device__ __forceinline__ short f2bf(float f) {
    union { float f; unsigned u; } v; v.f = f;
    unsigned r = v.u + 0x7FFFu + ((v.u >> 16) & 1u);   // RNE
    return (short)(r >> 16);
}

__device__ __forceinline__ unsigned pk2(float a, float b) {
    float2 t; t.x = a; t.y = b;
    __hip_bfloat162 h = __float22bfloat162_rn(t);
    unsigned u; __builtin_memcpy(&u, &h, 4);
    return u;
}

__device__ __forceinline__ f32x4 mfma16(short8 a, short8 b, f32x4 c) {
    return __builtin_amdgcn_mfma_f32_16x16x32_bf16(a, b, c, 0, 0, 0);
}

// sqrt(0.125 * log2(e)): Qf pre-scaled so S^T = (Q')(Q')^T is directly in exp2 domain
#define SQRT_C 0.424660891f

// fp32 -> bf16 bulk convert, n multiple of 1024
__global__ __launch_bounds__(256) void cvtw(const float* __restrict__ a,
                                            short* __restrict__ o) {
    int i = blockIdx.x * 256 + threadIdx.x;
    float4 v = ((const float4*)a)[i];
    *(uint2v*)&o[i * 4] = (uint2v){pk2(v.x, v.y), pk2(v.z, v.w)};
}

// Fragment-major layouts (per bh, per 64-key tile = 4096 shorts, 8 chunks of 512):
//  Qf chunk(t4,s): lane L holds Q[key=16*t4+(L&15)][d=32*s+8*(L>>4)+j]  (SCALED by SQRT_C)
//  Vf chunk(t2,ks): lane L holds Q[key=32*ks+8*(L>>4)+j][d=16*t2+(L&15)] (unscaled)

// C[M,N] = A[M,K] @ W[N,K]^T, M=8192, N=768, K=768. A bf16, W fp32 (cvt in staging).
// Tile 128m x 64n, BK=64, 768 blocks, XCD-affine m. MODE 0: C fp32 row-major.
// MODE 1: emit Qf (scaled) + Vf fragment-major bf16 via LDS scatter->coalesced flush.
template <int MODE>
__global__ __launch_bounds__(256, 3) void gemm_nt(const short* __restrict__ A,
                                                  const float* __restrict__ W,
                                                  void* __restrict__ Cp,
                                                  short* __restrict__ Vf) {
    __shared__ short As[128 * 72];   // 64 K-elems + 8 pad; reused as F scratch in epilogue
    __shared__ short Bs[64 * 72];
    const int t = threadIdx.x;
    const int lane = t & 63, w = t >> 6;
    const int lr = lane & 15, qd = lane >> 4;
    const int wm = (w & 1) * 64, wn = (w >> 1) * 32;
    const int lin = blockIdx.x;
    const int xcd = lin & 7, jj = lin >> 3;
    const int nt = jj % 12, mt = (jj / 12) * 8 + xcd;
    const int m0 = mt * 128, n0 = nt * 64;

    f32x4 acc[4][2];
#pragma unroll
    for (int i = 0; i < 4; ++i)
#pragma unroll
        for (int j = 0; j < 2; ++j) acc[i][j] = (f32x4){0.f, 0.f, 0.f, 0.f};

#pragma unroll
    for (int u = 0; u < 4; ++u) {
        int c = t + 256 * u, row = c >> 3, col = (c & 7) << 3;
        *(short8*)&As[row * 72 + col] = *(const short8*)&A[(size_t)(m0 + row) * DQ + col];
    }
#pragma unroll
    for (int u = 0; u < 4; ++u) {
        int c = t + 256 * u, row = c >> 4, col = (c & 15) << 2;
        float4 v = *(const float4*)&W[(size_t)(n0 + row) * DQ + col];
        *(uint2v*)&Bs[row * 72 + col] = (uint2v){pk2(v.x, v.y), pk2(v.z, v.w)};
    }
    __syncthreads();

    for (int kt = 0; kt < 12; ++kt) {
        short8 ra[4]; float4 rb[4];
        if (kt < 11) {
            const int k0 = (kt + 1) * 64;
#pragma unroll
            for (int u = 0; u < 4; ++u) {
                int c = t + 256 * u, row = c >> 3, col = (c & 7) << 3;
                ra[u] = *(const short8*)&A[(size_t)(m0 + row) * DQ + k0 + col];
            }
#pragma unroll
            for (int u = 0; u < 4; ++u) {
                int c = t + 256 * u, row = c >> 4, col = (c & 15) << 2;
                rb[u] = *(const float4*)&W[(size_t)(n0 + row) * DQ + k0 + col];
            }
        }
#pragma unroll
        for (int s = 0; s < 2; ++s) {
            short8 af[4], bf[2];
#pragma unroll
            for (int i = 0; i < 4; ++i)
                af[i] = *(short8*)&As[(wm + 16 * i + lr) * 72 + 32 * s + qd * 8];
#pragma unroll
            for (int j = 0; j < 2; ++j)
                bf[j] = *(short8*)&Bs[(wn + 16 * j + lr) * 72 + 32 * s + qd * 8];
#pragma unroll
            for (int i = 0; i < 4; ++i)
#pragma unroll
                for (int j = 0; j < 2; ++j)
                    acc[i][j] = mfma16(af[i], bf[j], acc[i][j]);
        }
        if (kt < 11) {
            __syncthreads();
#pragma unroll
            for (int u = 0; u < 4; ++u) {
                int c = t + 256 * u, row = c >> 3, col = (c & 7) << 3;
                *(short8*)&As[row * 72 + col] = ra[u];
            }
#pragma unroll
            for (int u = 0; u < 4; ++u) {
                int c = t + 256 * u, row = c >> 4, col = (c & 15) << 2;
                *(uint2v*)&Bs[row * 72 + col] = (uint2v){pk2(rb[u].x, rb[u].y), pk2(rb[u].z, rb[u].w)};
            }
            __syncthreads();
        }
    }

    if (MODE == 0) {
#pragma unroll
        for (int i = 0; i < 4; ++i)
#pragma unroll
            for (int j = 0; j < 2; ++j) {
                const int row0 = m0 + wm + 16 * i + qd * 4;
                const int col = n0 + wn + 16 * j + lr;
#pragma unroll
                for (int r = 0; r < 4; ++r)
                    ((float*)Cp)[(size_t)(row0 + r) * DQ + col] = acc[i][j][r];
            }
    } else {
        // tile = keys (m0&4095)..+127 of bh = (m0>>12)*12 + nt, dims 0..63 (hs)
        short* Qf = (short*)Cp;
        short* F = As;                                   // 8192-short scratch
        const int bh = (m0 >> 12) * NH + nt;
        const size_t gbase = (size_t)bh * (LQ * 64) + (size_t)(((m0 & 4095) >> 6) << 12);
        __syncthreads();
        // ---- Vf staging (unscaled): packed b64 scatter ----
#pragma unroll
        for (int i = 0; i < 4; ++i)
#pragma unroll
            for (int j = 0; j < 2; ++j) {
                const int kl = wm + 16 * i + qd * 4;     // key base (4 consecutive)
                const int hs = wn + 16 * j + lr;         // d
                const int fi = ((kl >> 6) << 12) + ((((hs >> 4) << 1) + ((kl >> 5) & 1)) << 9)
                             + (((hs & 15) + (((kl >> 3) & 3) << 4)) << 3) + (kl & 7);
                *(uint2v*)&F[fi] = (uint2v){pk2(acc[i][j][0], acc[i][j][1]),
                                            pk2(acc[i][j][2], acc[i][j][3])};
            }
        __syncthreads();
#pragma unroll
        for (int p = 0; p < 4; ++p) {
            int u = t + 256 * p;
            *(short8*)&Vf[gbase + (size_t)u * 8] = *(short8*)&F[u * 8];
        }
        __syncthreads();
        // ---- Qf staging (scaled by SQRT_C): b16 scatter ----
#pragma unroll
        for (int i = 0; i < 4; ++i)
#pragma unroll
            for (int j = 0; j < 2; ++j) {
                const int hs = wn + 16 * j + lr;
#pragma unroll
                for (int r = 0; r < 4; ++r) {
                    const int key = wm + 16 * i + qd * 4 + r;
                    const int fi = ((key >> 6) << 12) + (((((key >> 4) & 3) << 1) + (hs >> 5)) << 9)
                                 + (((qd * 4 + r) + (((hs >> 3) & 3) << 4)) << 3) + (hs & 7);
                    F[fi] = f2bf(acc[i][j][r] * SQRT_C);
                }
            }
        __syncthreads();
#pragma unroll
        for (int p = 0; p < 4; ++p) {
            int u = t + 256 * p;
            *(short8*)&Qf[gbase + (size_t)u * 8] = *(short8*)&F[u * 8];
        }
    }
}

// Barrier-free flash attention, K=V=Q, shift-0 softmax, fragment-major global loads.
// 64 queries/wave (4 independent m-tile chains), 2-wave blocks, 768 blocks = 3/CU.
// Halves L2/TA bytes per q*k vs 32q/wave and doubles per-wave ILP (the round-10
// counters showed ~80% stall with per-SIMD pipes <12% busy). Per-m-tile Ps buffers
// so the 4 chains have no LDS WAR hazards. l via ones-MFMA (r10-verified mapping).
__global__ __launch_bounds__(128, 2) void attn(const short* __restrict__ Qf,
                                               const short* __restrict__ Vf,
                                               short* __restrict__ O) {
    const int linear = blockIdx.x;
    const int xcd = linear & 7, slot = linear >> 3;        // 768 blocks, 8 XCDs
    const int bh = 3 * xcd + (slot >> 5);                  // 3 bh per XCD (L2-resident)
    const int qtile = slot & 31;                           // 32 q-tiles of 128
    const int t = threadIdx.x;
    const int lane = t & 63, w = t >> 6;                   // w in {0,1}
    const int lr = lane & 15, qd = lane >> 4;

    __shared__ short Ps[2][4][16 * 72];                    // [wave][m-tile][q][key]

    const short* Qbh = Qf + (size_t)bh * (LQ * 64);
    const short* Vbh = Vf + (size_t)bh * (LQ * 64);
    const int q0 = qtile * 128 + w * 64;

    const short one_bf = (short)0x3F80;                    // bf16 1.0
    short8 ones;
#pragma unroll
    for (int j = 0; j < 8; ++j) ones[j] = one_bf;

    // Q B-frags: chunk-linear addr = g*1024 + s*512 + lane*8
    short8 aq[4][2];
#pragma unroll
    for (int i = 0; i < 4; ++i) {
        const int g = (q0 >> 4) + i;
#pragma unroll
        for (int s = 0; s < 2; ++s)
            aq[i][s] = *(const short8*)&Qbh[g * 1024 + s * 512 + lane * 8];
    }

    f32x4 oacc[4][4], lacc[4];
#pragma unroll
    for (int i = 0; i < 4; ++i) {
        lacc[i] = (f32x4){0.f, 0.f, 0.f, 0.f};
#pragma unroll
        for (int t2 = 0; t2 < 4; ++t2) oacc[i][t2] = (f32x4){0.f, 0.f, 0.f, 0.f};
    }

    // prologue: kf for kb=0
    short8 kf[4][2];
#pragma unroll
    for (int t4 = 0; t4 < 4; ++t4)
#pragma unroll
        for (int s = 0; s < 2; ++s)
            kf[t4][s] = *(const short8*)&Qbh[(t4 * 2 + s) * 512 + lane * 8];

    for (int kb = 0; kb < LQ / 64; ++kb) {
        // current V^T frags + next-iter K frags: coalesced b128, issued up front
        short8 vb[4][2];
#pragma unroll
        for (int t2 = 0; t2 < 4; ++t2)
#pragma unroll
            for (int ks = 0; ks < 2; ++ks)
                vb[t2][ks] = *(const short8*)&Vbh[kb * 4096 + (t2 * 2 + ks) * 512 + lane * 8];
        short8 kfn[4][2];
        if (kb < LQ / 64 - 1) {
#pragma unroll
            for (int t4 = 0; t4 < 4; ++t4)
#pragma unroll
                for (int s = 0; s < 2; ++s)
                    kfn[t4][s] = *(const short8*)&Qbh[(kb + 1) * 4096 + (t4 * 2 + s) * 512 + lane * 8];
        }

        // 4 independent m-tile chains: S^T (exp2 domain) -> exp -> Ps -> PV + l-MFMA
#pragma unroll
        for (int i = 0; i < 4; ++i) {
            f32x4 sacc[4];
#pragma unroll
            for (int t4 = 0; t4 < 4; ++t4) {
                sacc[t4] = (f32x4){0.f, 0.f, 0.f, 0.f};
#pragma unroll
                for (int s = 0; s < 2; ++s)
                    sacc[t4] = mfma16(kf[t4][s], aq[i][s], sacc[t4]);
            }
#pragma unroll
            for (int t4 = 0; t4 < 4; ++t4) {
                float p0 = __builtin_amdgcn_exp2f(sacc[t4][0]);
                float p1 = __builtin_amdgcn_exp2f(sacc[t4][1]);
                float p2 = __builtin_amdgcn_exp2f(sacc[t4][2]);
                float p3 = __builtin_amdgcn_exp2f(sacc[t4][3]);
                *(uint2v*)&Ps[w][i][lr * 72 + 16 * t4 + 4 * qd] =
                    (uint2v){pk2(p0, p1), pk2(p2, p3)};
            }
#pragma unroll
            for (int ks = 0; ks < 2; ++ks) {
                short8 pa = *(short8*)&Ps[w][i][lr * 72 + 32 * ks + qd * 8];
#pragma unroll
                for (int t2 = 0; t2 < 4; ++t2)
                    oacc[i][t2] = mfma16(pa, vb[t2][ks], oacc[i][t2]);
                lacc[i] = mfma16(pa, ones, lacc[i]);   // row-sum on the MFMA pipe
            }
        }
#pragma unroll
        for (int t4 = 0; t4 < 4; ++t4)
#pragma unroll
            for (int s = 0; s < 2; ++s) kf[t4][s] = kfn[t4][s];
    }

    // l for query qd*4+r is lacc[i][r] in every lane; normalize; store O[b][l][h*64+e]
    const int b = bh / NH, h = bh % NH;
#pragma unroll
    for (int i = 0; i < 4; ++i) {
        float inv[4];
#pragma unroll
        for (int r = 0; r < 4; ++r) inv[r] = 1.0f / lacc[i][r];
#pragma unroll
        for (int t2 = 0; t2 < 4; ++t2)
#pragma unroll
            for (int r = 0; r < 4; ++r) {
                int lq = q0 + 16 * i + qd * 4 + r;
                int e = h * 64 + 16 * t2 + lr;
                O[((size_t)(b * LQ + lq)) * DQ + e] = f2bf(oacc[i][t2][r] * inv[r]);
            }
    }
}

extern "C" void kernel_launch(void* const* d_in, const int* in_sizes, int n_in,
                              void* d_out, int out_size, void* d_ws, size_t ws_size,
                              hipStream_t stream) {
    (void)in_sizes; (void)n_in; (void)out_size; (void)ws_size;
    const float* x  = (const float*)d_in[0];   // fp32 [2,4096,768]
    const float* Wq = (const float*)d_in[1];   // fp32 [768,768]
    const float* Wo = (const float*)d_in[2];   // fp32 [768,768]
    float* out = (float*)d_out;                // fp32 [2,4096,768]

    const size_t NQ = (size_t)NB * NH * LQ * 64;         // 6,291,456 elements
    short* Qf  = (short*)d_ws;                           // fragment-major scaled Q
    short* Vfb = Qf + NQ;                                // fragment-major unscaled Q (V)
    short* Ows = Vfb + NQ;                               // xb, then attention out

    // 1) x -> bf16 (into Ows slot)
    cvtw<<<(NB * LQ * DQ) / 1024, 256, 0, stream>>>(x, Ows);
    // 2) Q-projection -> fragment-major Qf (scaled) + Vf
    gemm_nt<1><<<768, 256, 0, stream>>>(Ows, Wq, Qf, Vfb);
    // 3) barrier-free flash attention (K=V=Q), 64 q/wave -> Ows
    attn<<<768, 128, 0, stream>>>(Qf, Vfb, Ows);
    // 4) out = O @ bf16(Wo)^T, fp32 store
    gemm_nt<0><<<768, 256, 0, stream>>>(Ows, Wo, out, nullptr);
}